// Round 3
// baseline (217.972 us; speedup 1.0000x reference)
//
#include <hip/hip_runtime.h>
#include <hip/hip_bf16.h>

// EdgeDecoder: out[e] = relu(BN(W_a x[src] + W_b x[dst] + b1)) . w2 + b2
// R15 = R14 with k1 rebuilt as a barrier-free, LDS-free streaming MFMA kernel.
// Evidence (R14 rocprof): k1 = 44-48us with MfmaUtil 4.8%, VALUBusy 6.5%,
// HBM 1.7TB/s (20%), occupancy 22.5%, 400k LDS bank conflicts. Floor ~perf
// 12-16us. Diagnosis: stage->barrier->compute phases of co-resident blocks
// lockstep => HBM duty ~1/3, MFMA ~5%. Fix: each wave owns 16 rows x 256
// cols; A-fragments load straight from x (fp32->bf16 in-register, each row
// read once grid-wide), B-fragments from L1-resident Bt. No LDS, no syncs.
// Per-element math identical to R14's verified swapped-operand MFMA.
// k4/k2 frozen at R12 config (k4 fabric-saturated ~3.4TB/s, 43us).

#define H 128
#define NN 256
static constexpr int M_NODES = 100000;
static constexpr int E_EDGES = 600000;
static constexpr int SAMPLE_STRIDE = 16;
static constexpr int SAMPLE_N = E_EDGES / SAMPLE_STRIDE;   // 37500
static constexpr int NBUCKET = 64;

typedef __attribute__((ext_vector_type(8))) short bf16x8;
typedef __attribute__((ext_vector_type(4))) float f32x4;

__device__ __forceinline__ unsigned short f2bf(float f) {
    unsigned u = __float_as_uint(f);
    unsigned r = u + 0x7fffu + ((u >> 16) & 1u);   // RNE
    return (unsigned short)(r >> 16);
}
__device__ __forceinline__ float bflo(unsigned u) { return __uint_as_float(u << 16); }
__device__ __forceinline__ float bfhi(unsigned u) { return __uint_as_float(u & 0xffff0000u); }
__device__ __forceinline__ unsigned cvt_pk(float a, float b) {
    __hip_bfloat162 p = __float22bfloat162_rn(make_float2(a, b));   // RNE packed
    union { __hip_bfloat162 h; unsigned u; } c; c.h = p;
    return c.u;
}

// ---------------- K0: pack w1 -> Bt[n][k] bf16; zero stat buckets
__global__ __launch_bounds__(256) void k0_prep(const float* __restrict__ w1,
                                               unsigned short* __restrict__ Bt,
                                               float* __restrict__ stats) {
    int idx = blockIdx.x * 256 + threadIdx.x;      // 0..32767
    int n = idx >> 7, k = idx & 127;
    float v = (n < 128) ? w1[n * 256 + k] : w1[(n - 128) * 256 + 128 + k];
    Bt[idx] = f2bf(v);                              // Bt[n*128 + k]
    if (idx < 2 * NBUCKET * 128) stats[idx] = 0.f;
}

// ---------------- K1: UV = X @ Bt^T  (M x 256), bf16 out, MFMA 16x16x32
// Barrier-free: wave owns 16 rows x 256 cols. A direct from x (fp32->bf16
// in-register), B from L1/L2-resident Bt. Swapped-operand MFMA => lane
// holds 4 consecutive output cols -> packed 8B direct stores.
__global__ __launch_bounds__(256) void k1_uv(const float* __restrict__ x,
                                             const unsigned short* __restrict__ Bt,
                                             unsigned short* __restrict__ UV) {
    const int t = threadIdx.x;
    const int wave = t >> 6, lane = t & 63;
    const int r16 = lane & 15, q = lane >> 4;

    const int row  = blockIdx.x * 64 + wave * 16 + r16;
    const int rowc = (row < M_NODES) ? row : (M_NODES - 1);
    const float* __restrict__ xr = x + rowc * H;

    f32x4 acc[16];
    #pragma unroll
    for (int ct = 0; ct < 16; ++ct) acc[ct] = (f32x4){0.f, 0.f, 0.f, 0.f};

    #pragma unroll
    for (int ks = 0; ks < 4; ++ks) {
        // A fragment: lane(r16,q) holds x[row][ks*32+q*8 .. +7] as bf16
        float4 v0 = *(const float4*)(xr + ks * 32 + q * 8);
        float4 v1 = *(const float4*)(xr + ks * 32 + q * 8 + 4);
        union { bf16x8 v; unsigned u[4]; } a;
        a.u[0] = cvt_pk(v0.x, v0.y);
        a.u[1] = cvt_pk(v0.z, v0.w);
        a.u[2] = cvt_pk(v1.x, v1.y);
        a.u[3] = cvt_pk(v1.z, v1.w);
        #pragma unroll
        for (int ct = 0; ct < 16; ++ct) {
            bf16x8 b = *(const bf16x8*)(Bt + (ct * 16 + r16) * H + ks * 32 + q * 8);
            // swapped operands: D'[n][m]; same product set as mfma(a,b) -> C^T
            acc[ct] = __builtin_amdgcn_mfma_f32_16x16x32_bf16(b, a.v, acc[ct], 0, 0, 0);
        }
    }

    if (row < M_NODES) {
        unsigned short* __restrict__ o = UV + row * NN;
        #pragma unroll
        for (int ct = 0; ct < 16; ++ct) {
            uint2 pk = make_uint2(cvt_pk(acc[ct][0], acc[ct][1]),
                                  cvt_pk(acc[ct][2], acc[ct][3]));
            *(uint2*)(o + ct * 16 + q * 4) = pk;
        }
    }
}

// ---------------- K2s: sampled stats over z' = u+v (b1 dropped; exact fold)
__global__ __launch_bounds__(256) void k2_sstats(const unsigned short* __restrict__ UV,
                                                 const int* __restrict__ ei,
                                                 float* __restrict__ gsum,
                                                 float* __restrict__ gss) {
    __shared__ float ssum[128], sss[128];
    const int t = threadIdx.x;
    if (t < 128) { ssum[t] = 0.f; sss[t] = 0.f; }
    __syncthreads();

    const int sub = t & 15;                         // 16 lanes per edge
    const int gid = (blockIdx.x * 256 + t) >> 4;
    const int ngroups = gridDim.x * 16;

    float asum[8] = {0, 0, 0, 0, 0, 0, 0, 0};
    float ass[8]  = {0, 0, 0, 0, 0, 0, 0, 0};

    for (int i = gid; i < SAMPLE_N; i += ngroups) {
        int e = i * SAMPLE_STRIDE;
        int2 p1 = ((const int2*)ei)[e];
        uint4 uu = *(const uint4*)(UV + p1.x * NN + sub * 8);
        uint4 vv = *(const uint4*)(UV + p1.y * NN + 128 + sub * 8);
        #define ACC2(ua, va, j0)                                              \
        {   float z0 = bflo(ua) + bflo(va);                                   \
            asum[j0] += z0; ass[j0] += z0 * z0;                               \
            float z1 = bfhi(ua) + bfhi(va);                                   \
            asum[j0 + 1] += z1; ass[j0 + 1] += z1 * z1; }
        ACC2(uu.x, vv.x, 0) ACC2(uu.y, vv.y, 2) ACC2(uu.z, vv.z, 4) ACC2(uu.w, vv.w, 6)
        #undef ACC2
    }
    #pragma unroll
    for (int j = 0; j < 8; ++j) {
        atomicAdd(&ssum[sub * 8 + j], asum[j]);
        atomicAdd(&sss[sub * 8 + j], ass[j]);
    }
    __syncthreads();
    const int bkt = (blockIdx.x & (NBUCKET - 1)) * 128;
    if (t < 128) atomicAdd(&gsum[bkt + t], ssum[t]);
    else         atomicAdd(&gss[bkt + t - 128], sss[t - 128]);
}

// ---------------- K3: reduce buckets; A = gamma*rsqrt(var+eps), C = beta - mean'*A
__global__ void k3_fin(const float* __restrict__ gsum, const float* __restrict__ gss,
                       const float* __restrict__ gamma, const float* __restrict__ beta,
                       float* __restrict__ Ab, float* __restrict__ Cb) {
    int t = threadIdx.x;  // 128
    float s = 0.f, ss = 0.f;
    for (int b = 0; b < NBUCKET; ++b) { s += gsum[b * 128 + t]; ss += gss[b * 128 + t]; }
    const float inv_n = 1.f / SAMPLE_N;
    float mean = s * inv_n;                       // mean of z' = mean_z - b1
    float var  = ss * inv_n - mean * mean;        // var unchanged by constant shift
    float inv  = rsqrtf(var + 1e-5f);
    float a = gamma[t] * inv;
    Ab[t] = a;
    Cb[t] = beta[t] - mean * a;
}

// ---------------- K4: full gather; out[e] = relu(A*(u+v)+C).w + b2. unroll2 @1024
__global__ __launch_bounds__(256) void k4_gather(const unsigned short* __restrict__ UV,
                                                 const int* __restrict__ ei,
                                                 const float* __restrict__ Ab,
                                                 const float* __restrict__ Cb,
                                                 const float* __restrict__ w2,
                                                 const float* __restrict__ b2,
                                                 float* __restrict__ out) {
    const int t = threadIdx.x;
    const int sub = t & 15;
    const int gid = (blockIdx.x * 256 + t) >> 4;
    const int ngroups = gridDim.x * 16;

    float Ar[8], Cr[8], wr[8];
    #pragma unroll
    for (int j = 0; j < 8; ++j) {
        int h = sub * 8 + j;
        Ar[j] = Ab[h]; Cr[j] = Cb[h]; wr[j] = w2[h];
    }
    const float bb2 = b2[0];

    for (int e = gid; e < E_EDGES; e += 2 * ngroups) {
        int e2 = e + ngroups;
        bool has2 = e2 < E_EDGES;
        int2 p1 = ((const int2*)ei)[e];
        int2 p2 = has2 ? ((const int2*)ei)[e2] : p1;
        uint4 uu  = *(const uint4*)(UV + p1.x * NN + sub * 8);
        uint4 vv  = *(const uint4*)(UV + p1.y * NN + 128 + sub * 8);
        uint4 uu2 = *(const uint4*)(UV + p2.x * NN + sub * 8);
        uint4 vv2 = *(const uint4*)(UV + p2.y * NN + 128 + sub * 8);
        #define DOT2(acc, ua, va, j0)                                         \
        {   float z0 = bflo(ua) + bflo(va);                                   \
            acc += fmaxf(fmaf(z0, Ar[j0], Cr[j0]), 0.f) * wr[j0];             \
            float z1 = bfhi(ua) + bfhi(va);                                   \
            acc += fmaxf(fmaf(z1, Ar[j0 + 1], Cr[j0 + 1]), 0.f) * wr[j0 + 1]; }
        float p = 0.f, q = 0.f;
        DOT2(p, uu.x, vv.x, 0) DOT2(p, uu.y, vv.y, 2)
        DOT2(p, uu.z, vv.z, 4) DOT2(p, uu.w, vv.w, 6)
        DOT2(q, uu2.x, vv2.x, 0) DOT2(q, uu2.y, vv2.y, 2)
        DOT2(q, uu2.z, vv2.z, 4) DOT2(q, uu2.w, vv2.w, 6)
        #undef DOT2
        p += __shfl_xor(p, 1);  q += __shfl_xor(q, 1);
        p += __shfl_xor(p, 2);  q += __shfl_xor(q, 2);
        p += __shfl_xor(p, 4);  q += __shfl_xor(q, 4);
        p += __shfl_xor(p, 8);  q += __shfl_xor(q, 8);
        if (sub == 0) {
            out[e] = p + bb2;
            if (has2) out[e2] = q + bb2;
        }
    }
}

extern "C" void kernel_launch(void* const* d_in, const int* in_sizes, int n_in,
                              void* d_out, int out_size, void* d_ws, size_t ws_size,
                              hipStream_t stream) {
    const float* x     = (const float*)d_in[0];
    const int*   ei    = (const int*)d_in[1];
    const float* w1    = (const float*)d_in[2];
    const float* gamma = (const float*)d_in[4];
    const float* beta  = (const float*)d_in[5];
    const float* w2    = (const float*)d_in[6];
    const float* b2    = (const float*)d_in[7];
    float* out = (float*)d_out;

    char* w = (char*)d_ws;
    unsigned short* UV = (unsigned short*)w;                       // 51,200,000 B
    unsigned short* Bt = (unsigned short*)(w + 51200000);          // 65,536 B
    float* gsum = (float*)(w + 51265536);                          // 64*128 f
    float* gss  = gsum + NBUCKET * 128;                            // 64*128 f
    float* Ab   = (float*)(w + 51265536 + 2 * NBUCKET * 128 * 4);  // 128 f
    float* Cb   = Ab + 128;                                        // 128 f

    k0_prep<<<128, 256, 0, stream>>>(w1, Bt, gsum);
    k1_uv<<<(M_NODES + 63) / 64, 256, 0, stream>>>(x, Bt, UV);
    k2_sstats<<<512, 256, 0, stream>>>(UV, ei, gsum, gss);
    k3_fin<<<1, 128, 0, stream>>>(gsum, gss, gamma, beta, Ab, Cb);
    k4_gather<<<1024, 256, 0, stream>>>(UV, ei, Ab, Cb, w2, b2, out);
}

// Round 4
// 189.560 us; speedup vs baseline: 1.1499x; 1.1499x over previous
//
#include <hip/hip_runtime.h>
#include <hip/hip_bf16.h>

// EdgeDecoder: out[e] = relu(BN(W_a x[src] + W_b x[dst] + b1)) . w2 + b2
// R16: k1 rebuilt around the load-dependency diagnosis.
// Evidence (R15 rocprof): k1 76us = ~28k cy/wave ~= 64 serialized Bt-load->MFMA
// round-trips (~400cy each). Occupancy UP vs R14 yet slower => not occupancy,
// not LDS, not stores: it's the dependent-load chain feeding every MFMA.
// Fix: Bt (64KB, block-invariant) fragments preloaded ONCE into 64 VGPRs per
// wave (wave owns a 64-col group); wave then streams 16-row tiles:
// 8 independent x loads -> cvt -> 16 reg-fed MFMAs -> 4 packed stores.
// No LDS, no barriers, no loads on the MFMA critical path. 100000 = 6250*16,
// so no row remainder. Numerics bit-identical to R15 (passed, absmax 0.015625).
// k2/k4 frozen at R12 config (k4 fabric-saturated ~3.4TB/s, 43us).

#define H 128
#define NN 256
static constexpr int M_NODES = 100000;
static constexpr int E_EDGES = 600000;
static constexpr int SAMPLE_STRIDE = 16;
static constexpr int SAMPLE_N = E_EDGES / SAMPLE_STRIDE;   // 37500
static constexpr int NBUCKET = 64;
static constexpr int NTILES = M_NODES / 16;                // 6250 exact

typedef __attribute__((ext_vector_type(8))) short bf16x8;
typedef __attribute__((ext_vector_type(4))) float f32x4;

__device__ __forceinline__ unsigned short f2bf(float f) {
    unsigned u = __float_as_uint(f);
    unsigned r = u + 0x7fffu + ((u >> 16) & 1u);   // RNE
    return (unsigned short)(r >> 16);
}
__device__ __forceinline__ float bflo(unsigned u) { return __uint_as_float(u << 16); }
__device__ __forceinline__ float bfhi(unsigned u) { return __uint_as_float(u & 0xffff0000u); }
__device__ __forceinline__ unsigned cvt_pk(float a, float b) {
    __hip_bfloat162 p = __float22bfloat162_rn(make_float2(a, b));   // RNE packed
    union { __hip_bfloat162 h; unsigned u; } c; c.h = p;
    return c.u;
}

// ---------------- K0: pack w1 -> Bt[n][k] bf16; zero stat buckets
__global__ __launch_bounds__(256) void k0_prep(const float* __restrict__ w1,
                                               unsigned short* __restrict__ Bt,
                                               float* __restrict__ stats) {
    int idx = blockIdx.x * 256 + threadIdx.x;      // 0..32767
    int n = idx >> 7, k = idx & 127;
    float v = (n < 128) ? w1[n * 256 + k] : w1[(n - 128) * 256 + 128 + k];
    Bt[idx] = f2bf(v);                              // Bt[n*128 + k]
    if (idx < 2 * NBUCKET * 128) stats[idx] = 0.f;
}

// ---------------- K1: UV = X @ Bt^T  (M x 256), bf16 out, MFMA 16x16x32
// Wave owns 64 cols; all 16 B-fragments preloaded to VGPRs (block-invariant).
// Streams 16-row tiles: 8 independent x loads, reg-fed MFMAs, direct stores.
__global__ __launch_bounds__(256) void k1_uv(const float* __restrict__ x,
                                             const unsigned short* __restrict__ Bt,
                                             unsigned short* __restrict__ UV) {
    const int t = threadIdx.x;
    const int wave = t >> 6, lane = t & 63;
    const int r16 = lane & 15, q = lane >> 4;
    const int c0 = wave * 64;

    // Preload ALL B fragments for this wave's 64-col group: 16 x 16B = 64 VGPR.
    bf16x8 bfr[4][4];
    #pragma unroll
    for (int ct = 0; ct < 4; ++ct)
        #pragma unroll
        for (int ks = 0; ks < 4; ++ks)
            bfr[ct][ks] = *(const bf16x8*)(Bt + (c0 + ct * 16 + r16) * H + ks * 32 + q * 8);

    const int xoff = q * 8;

    for (int tt = blockIdx.x; tt < NTILES; tt += gridDim.x) {
        const int row = tt * 16 + r16;              // always < 100000
        const float* __restrict__ xr = x + row * H;

        // 8 independent 16B loads: lane's full k-range, one latency for all
        float4 xv[8];
        #pragma unroll
        for (int ks = 0; ks < 4; ++ks) {
            xv[2 * ks]     = *(const float4*)(xr + ks * 32 + xoff);
            xv[2 * ks + 1] = *(const float4*)(xr + ks * 32 + xoff + 4);
        }
        union { bf16x8 v; unsigned u[4]; } a[4];
        #pragma unroll
        for (int ks = 0; ks < 4; ++ks) {
            a[ks].u[0] = cvt_pk(xv[2 * ks].x, xv[2 * ks].y);
            a[ks].u[1] = cvt_pk(xv[2 * ks].z, xv[2 * ks].w);
            a[ks].u[2] = cvt_pk(xv[2 * ks + 1].x, xv[2 * ks + 1].y);
            a[ks].u[3] = cvt_pk(xv[2 * ks + 1].z, xv[2 * ks + 1].w);
        }

        f32x4 acc[4];
        #pragma unroll
        for (int ct = 0; ct < 4; ++ct) acc[ct] = (f32x4){0.f, 0.f, 0.f, 0.f};
        #pragma unroll
        for (int ks = 0; ks < 4; ++ks)
            #pragma unroll
            for (int ct = 0; ct < 4; ++ct)
                acc[ct] = __builtin_amdgcn_mfma_f32_16x16x32_bf16(bfr[ct][ks], a[ks].v, acc[ct], 0, 0, 0);

        // D' layout: lane holds 4 consecutive cols (reg dim) of row `row`
        unsigned short* __restrict__ o = UV + row * NN + c0;
        #pragma unroll
        for (int ct = 0; ct < 4; ++ct) {
            uint2 pk = make_uint2(cvt_pk(acc[ct][0], acc[ct][1]),
                                  cvt_pk(acc[ct][2], acc[ct][3]));
            *(uint2*)(o + ct * 16 + q * 4) = pk;
        }
    }
}

// ---------------- K2s: sampled stats over z' = u+v (b1 dropped; exact fold)
__global__ __launch_bounds__(256) void k2_sstats(const unsigned short* __restrict__ UV,
                                                 const int* __restrict__ ei,
                                                 float* __restrict__ gsum,
                                                 float* __restrict__ gss) {
    __shared__ float ssum[128], sss[128];
    const int t = threadIdx.x;
    if (t < 128) { ssum[t] = 0.f; sss[t] = 0.f; }
    __syncthreads();

    const int sub = t & 15;                         // 16 lanes per edge
    const int gid = (blockIdx.x * 256 + t) >> 4;
    const int ngroups = gridDim.x * 16;

    float asum[8] = {0, 0, 0, 0, 0, 0, 0, 0};
    float ass[8]  = {0, 0, 0, 0, 0, 0, 0, 0};

    for (int i = gid; i < SAMPLE_N; i += ngroups) {
        int e = i * SAMPLE_STRIDE;
        int2 p1 = ((const int2*)ei)[e];
        uint4 uu = *(const uint4*)(UV + p1.x * NN + sub * 8);
        uint4 vv = *(const uint4*)(UV + p1.y * NN + 128 + sub * 8);
        #define ACC2(ua, va, j0)                                              \
        {   float z0 = bflo(ua) + bflo(va);                                   \
            asum[j0] += z0; ass[j0] += z0 * z0;                               \
            float z1 = bfhi(ua) + bfhi(va);                                   \
            asum[j0 + 1] += z1; ass[j0 + 1] += z1 * z1; }
        ACC2(uu.x, vv.x, 0) ACC2(uu.y, vv.y, 2) ACC2(uu.z, vv.z, 4) ACC2(uu.w, vv.w, 6)
        #undef ACC2
    }
    #pragma unroll
    for (int j = 0; j < 8; ++j) {
        atomicAdd(&ssum[sub * 8 + j], asum[j]);
        atomicAdd(&sss[sub * 8 + j], ass[j]);
    }
    __syncthreads();
    const int bkt = (blockIdx.x & (NBUCKET - 1)) * 128;
    if (t < 128) atomicAdd(&gsum[bkt + t], ssum[t]);
    else         atomicAdd(&gss[bkt + t - 128], sss[t - 128]);
}

// ---------------- K3: reduce buckets; A = gamma*rsqrt(var+eps), C = beta - mean'*A
__global__ void k3_fin(const float* __restrict__ gsum, const float* __restrict__ gss,
                       const float* __restrict__ gamma, const float* __restrict__ beta,
                       float* __restrict__ Ab, float* __restrict__ Cb) {
    int t = threadIdx.x;  // 128
    float s = 0.f, ss = 0.f;
    for (int b = 0; b < NBUCKET; ++b) { s += gsum[b * 128 + t]; ss += gss[b * 128 + t]; }
    const float inv_n = 1.f / SAMPLE_N;
    float mean = s * inv_n;                       // mean of z' = mean_z - b1
    float var  = ss * inv_n - mean * mean;        // var unchanged by constant shift
    float inv  = rsqrtf(var + 1e-5f);
    float a = gamma[t] * inv;
    Ab[t] = a;
    Cb[t] = beta[t] - mean * a;
}

// ---------------- K4: full gather; out[e] = relu(A*(u+v)+C).w + b2. unroll2 @1024
__global__ __launch_bounds__(256) void k4_gather(const unsigned short* __restrict__ UV,
                                                 const int* __restrict__ ei,
                                                 const float* __restrict__ Ab,
                                                 const float* __restrict__ Cb,
                                                 const float* __restrict__ w2,
                                                 const float* __restrict__ b2,
                                                 float* __restrict__ out) {
    const int t = threadIdx.x;
    const int sub = t & 15;
    const int gid = (blockIdx.x * 256 + t) >> 4;
    const int ngroups = gridDim.x * 16;

    float Ar[8], Cr[8], wr[8];
    #pragma unroll
    for (int j = 0; j < 8; ++j) {
        int h = sub * 8 + j;
        Ar[j] = Ab[h]; Cr[j] = Cb[h]; wr[j] = w2[h];
    }
    const float bb2 = b2[0];

    for (int e = gid; e < E_EDGES; e += 2 * ngroups) {
        int e2 = e + ngroups;
        bool has2 = e2 < E_EDGES;
        int2 p1 = ((const int2*)ei)[e];
        int2 p2 = has2 ? ((const int2*)ei)[e2] : p1;
        uint4 uu  = *(const uint4*)(UV + p1.x * NN + sub * 8);
        uint4 vv  = *(const uint4*)(UV + p1.y * NN + 128 + sub * 8);
        uint4 uu2 = *(const uint4*)(UV + p2.x * NN + sub * 8);
        uint4 vv2 = *(const uint4*)(UV + p2.y * NN + 128 + sub * 8);
        #define DOT2(acc, ua, va, j0)                                         \
        {   float z0 = bflo(ua) + bflo(va);                                   \
            acc += fmaxf(fmaf(z0, Ar[j0], Cr[j0]), 0.f) * wr[j0];             \
            float z1 = bfhi(ua) + bfhi(va);                                   \
            acc += fmaxf(fmaf(z1, Ar[j0 + 1], Cr[j0 + 1]), 0.f) * wr[j0 + 1]; }
        float p = 0.f, q = 0.f;
        DOT2(p, uu.x, vv.x, 0) DOT2(p, uu.y, vv.y, 2)
        DOT2(p, uu.z, vv.z, 4) DOT2(p, uu.w, vv.w, 6)
        DOT2(q, uu2.x, vv2.x, 0) DOT2(q, uu2.y, vv2.y, 2)
        DOT2(q, uu2.z, vv2.z, 4) DOT2(q, uu2.w, vv2.w, 6)
        #undef DOT2
        p += __shfl_xor(p, 1);  q += __shfl_xor(q, 1);
        p += __shfl_xor(p, 2);  q += __shfl_xor(q, 2);
        p += __shfl_xor(p, 4);  q += __shfl_xor(q, 4);
        p += __shfl_xor(p, 8);  q += __shfl_xor(q, 8);
        if (sub == 0) {
            out[e] = p + bb2;
            if (has2) out[e2] = q + bb2;
        }
    }
}

extern "C" void kernel_launch(void* const* d_in, const int* in_sizes, int n_in,
                              void* d_out, int out_size, void* d_ws, size_t ws_size,
                              hipStream_t stream) {
    const float* x     = (const float*)d_in[0];
    const int*   ei    = (const int*)d_in[1];
    const float* w1    = (const float*)d_in[2];
    const float* gamma = (const float*)d_in[4];
    const float* beta  = (const float*)d_in[5];
    const float* w2    = (const float*)d_in[6];
    const float* b2    = (const float*)d_in[7];
    float* out = (float*)d_out;

    char* w = (char*)d_ws;
    unsigned short* UV = (unsigned short*)w;                       // 51,200,000 B
    unsigned short* Bt = (unsigned short*)(w + 51200000);          // 65,536 B
    float* gsum = (float*)(w + 51265536);                          // 64*128 f
    float* gss  = gsum + NBUCKET * 128;                            // 64*128 f
    float* Ab   = (float*)(w + 51265536 + 2 * NBUCKET * 128 * 4);  // 128 f
    float* Cb   = Ab + 128;                                        // 128 f

    k0_prep<<<128, 256, 0, stream>>>(w1, Bt, gsum);
    k1_uv<<<1024, 256, 0, stream>>>(x, Bt, UV);
    k2_sstats<<<512, 256, 0, stream>>>(UV, ei, gsum, gss);
    k3_fin<<<1, 128, 0, stream>>>(gsum, gss, gamma, beta, Ab, Cb);
    k4_gather<<<1024, 256, 0, stream>>>(UV, ei, Ab, Cb, w2, b2, out);
}